// Round 10
// baseline (354.905 us; speedup 1.0000x reference)
//
#include <hip/hip_runtime.h>

// AGRU: B=2048, T=200, D=U=64, fp32. v9: explicit-register asm, bug-fixed.
// r9 post-mortem found two proj bugs (store-data VGPR overwritten while the
// store was in flight; v_mov v8 -> immediate v_readlane cross-lane RAW) and
// one unvalidated instruction (v_pk_fma_f32 with SGPR-pair src). v9:
//  - plain v_fmac_f32 with single-SGPR src0 (compiler-proven pattern r1-r6)
//  - OCT blocks: 8 readlanes (s40-s47) then 16 fmacs -> >=7-instr SGPR
//    spacing, 8-instr acc-chain spacing
//  - proj: sums avoid v52/53 until vmcnt(1) retires store(i-1); v8 mov
//    hoisted 9 instrs before first readlane
// Register map: v64-127 = A-matrix rows (reg 64+j = W_A[j][u]),
// v128-191 = B-matrix rows. v8=h/x, v9=bg, v[12:17]=ptrs, v32-39=4+4 acc
// chains, v40-46=prefetch, v42/v50-53=temps. s40-47 broadcast, s48-52 loop.

typedef float f32x2 __attribute__((ext_vector_type(2)));

constexpr int BATCH = 2048;
constexpr int T_STEPS = 200;
constexpr int UDIM = 64;
constexpr int NROWS = BATCH * T_STEPS;   // 409600

#define STR_(x) #x
#define STR(x) STR_(x)

#define PTRLO(p) ((unsigned)(unsigned long long)(const void*)(p))
#define PTRHI(p) ((unsigned)(((unsigned long long)(const void*)(p)) >> 32))

// ---- weight loads: 128 coalesced dword loads into v64..v191 ----
#define WLD(R,O) "global_load_dword v" STR(R) ", v[10:11], off offset:" STR(O) "\n\t"
#define WBUMP \
  "v_add_co_u32 v10, vcc, 0x1000, v10\n\t" \
  "v_addc_co_u32 v11, vcc, 0, v11, vcc\n\t"

#define WIN16(R0,R1,R2,R3,R4,R5,R6,R7,R8,R9,R10,R11,R12,R13,R14,R15) \
  WLD(R0,0) WLD(R1,256) WLD(R2,512) WLD(R3,768) \
  WLD(R4,1024) WLD(R5,1280) WLD(R6,1536) WLD(R7,1792) \
  WLD(R8,2048) WLD(R9,2304) WLD(R10,2560) WLD(R11,2816) \
  WLD(R12,3072) WLD(R13,3328) WLD(R14,3584) WLD(R15,3840)

#define WLOAD_A \
  WIN16(64,65,66,67,68,69,70,71,72,73,74,75,76,77,78,79) WBUMP \
  WIN16(80,81,82,83,84,85,86,87,88,89,90,91,92,93,94,95) WBUMP \
  WIN16(96,97,98,99,100,101,102,103,104,105,106,107,108,109,110,111) WBUMP \
  WIN16(112,113,114,115,116,117,118,119,120,121,122,123,124,125,126,127)

#define WLOAD_B \
  WIN16(128,129,130,131,132,133,134,135,136,137,138,139,140,141,142,143) WBUMP \
  WIN16(144,145,146,147,148,149,150,151,152,153,154,155,156,157,158,159) WBUMP \
  WIN16(160,161,162,163,164,165,166,167,168,169,170,171,172,173,174,175) WBUMP \
  WIN16(176,177,178,179,180,181,182,183,184,185,186,187,188,189,190,191)

// ---- OCT: 8 readlanes then 16 fmacs (4 acc chains per matrix) ----
#define RL(S,J) "v_readlane_b32 " S ", v8, " STR(J) "\n\t"
#define FM(ACC,S,W) "v_fmac_f32 " ACC ", " S ", v" STR(W) "\n\t"

#define OCT(J0,J1,J2,J3,J4,J5,J6,J7, A0,A1,A2,A3,A4,A5,A6,A7, B0,B1,B2,B3,B4,B5,B6,B7) \
  RL("s40",J0) RL("s41",J1) RL("s42",J2) RL("s43",J3) \
  RL("s44",J4) RL("s45",J5) RL("s46",J6) RL("s47",J7) \
  FM("v32","s40",A0) FM("v36","s40",B0) \
  FM("v33","s41",A1) FM("v37","s41",B1) \
  FM("v34","s42",A2) FM("v38","s42",B2) \
  FM("v35","s43",A3) FM("v39","s43",B3) \
  FM("v32","s44",A4) FM("v36","s44",B4) \
  FM("v33","s45",A5) FM("v37","s45",B5) \
  FM("v34","s46",A6) FM("v38","s46",B6) \
  FM("v35","s47",A7) FM("v39","s47",B7)

#define DOT64 \
  OCT(0,1,2,3,4,5,6,7,          64,65,66,67,68,69,70,71,         128,129,130,131,132,133,134,135) \
  OCT(8,9,10,11,12,13,14,15,    72,73,74,75,76,77,78,79,         136,137,138,139,140,141,142,143) \
  OCT(16,17,18,19,20,21,22,23,  80,81,82,83,84,85,86,87,         144,145,146,147,148,149,150,151) \
  OCT(24,25,26,27,28,29,30,31,  88,89,90,91,92,93,94,95,         152,153,154,155,156,157,158,159) \
  OCT(32,33,34,35,36,37,38,39,  96,97,98,99,100,101,102,103,     160,161,162,163,164,165,166,167) \
  OCT(40,41,42,43,44,45,46,47,  104,105,106,107,108,109,110,111, 168,169,170,171,172,173,174,175) \
  OCT(48,49,50,51,52,53,54,55,  112,113,114,115,116,117,118,119, 176,177,178,179,180,181,182,183) \
  OCT(56,57,58,59,60,61,62,63,  120,121,122,123,124,125,126,127, 184,185,186,187,188,189,190,191)

#define ACC_ZERO \
  "v_mov_b32 v32, 0\n\t" "v_mov_b32 v33, 0\n\t" \
  "v_mov_b32 v34, 0\n\t" "v_mov_b32 v35, 0\n\t" \
  "v_mov_b32 v36, 0\n\t" "v_mov_b32 v37, 0\n\t" \
  "v_mov_b32 v38, 0\n\t" "v_mov_b32 v39, 0\n\t"

#define ACLOBBERS \
  "v8","v9","v10","v11","v12","v13","v14","v15","v16","v17", \
  "v32","v33","v34","v35","v36","v37","v38","v39","v40","v41","v42","v43", \
  "v44","v45","v46","v50","v51","v52","v53", \
  "v64","v65","v66","v67","v68","v69","v70","v71", \
  "v72","v73","v74","v75","v76","v77","v78","v79", \
  "v80","v81","v82","v83","v84","v85","v86","v87", \
  "v88","v89","v90","v91","v92","v93","v94","v95", \
  "v96","v97","v98","v99","v100","v101","v102","v103", \
  "v104","v105","v106","v107","v108","v109","v110","v111", \
  "v112","v113","v114","v115","v116","v117","v118","v119", \
  "v120","v121","v122","v123","v124","v125","v126","v127", \
  "v128","v129","v130","v131","v132","v133","v134","v135", \
  "v136","v137","v138","v139","v140","v141","v142","v143", \
  "v144","v145","v146","v147","v148","v149","v150","v151", \
  "v152","v153","v154","v155","v156","v157","v158","v159", \
  "v160","v161","v162","v163","v164","v165","v166","v167", \
  "v168","v169","v170","v171","v172","v173","v174","v175", \
  "v176","v177","v178","v179","v180","v181","v182","v183", \
  "v184","v185","v186","v187","v188","v189","v190","v191", \
  "s40","s41","s42","s43","s44","s45","s46","s47", \
  "s48","s49","s50","s51","s52","vcc","scc","memory"

// ---------------- Kernel 2: recurrence (asm core) ----------------
// 512 blocks x 256 = 2048 waves (2/SIMD), 1 batch row per wave.
__global__ __launch_bounds__(256, 2) void rec_kernel(
    const f32x2* __restrict__ pre, const float* __restrict__ att,
    const float* __restrict__ h0,  const float* __restrict__ w_hr,
    const float* __restrict__ w_hh,const float* __restrict__ b_hh,
    float* __restrict__ out)
{
    const int u   = threadIdx.x & 63;
    const int row = (int)((blockIdx.x * blockDim.x + threadIdx.x) >> 6);

    const float* wa = w_hr + u;
    const float* wb = w_hh + u;
    const f32x2* pp = pre + (size_t)row * T_STEPS * UDIM + u;
    const float* ap = att + (size_t)row * T_STEPS;
    float*       op = out + (size_t)row * T_STEPS * UDIM + u;
    const float h0v = h0[(size_t)row * UDIM + u];
    const float bgv = b_hh[u];

    asm volatile(
        "v_mov_b32 v10, %[walo]\n\t" "v_mov_b32 v11, %[wahi]\n\t"
        WLOAD_A
        "v_mov_b32 v10, %[wblo]\n\t" "v_mov_b32 v11, %[wbhi]\n\t"
        WLOAD_B
        "v_mov_b32 v12, %[prelo]\n\t" "v_mov_b32 v13, %[prehi]\n\t"
        "v_mov_b32 v14, %[attlo]\n\t" "v_mov_b32 v15, %[atthi]\n\t"
        "v_mov_b32 v16, %[outlo]\n\t" "v_mov_b32 v17, %[outhi]\n\t"
        "v_mov_b32 v8, %[h0v]\n\t"
        "v_mov_b32 v9, %[bgv]\n\t"
        // prologue: load pv(0),av(0); wait all (incl. weights); issue pv(1),av(1)
        "global_load_dwordx2 v[40:41], v[12:13], off\n\t"
        "global_load_dword v42, v[14:15], off\n\t"
        "v_add_co_u32 v12, vcc, 0x200, v12\n\t"
        "v_addc_co_u32 v13, vcc, 0, v13, vcc\n\t"
        "v_add_co_u32 v14, vcc, 4, v14\n\t"
        "v_addc_co_u32 v15, vcc, 0, v15, vcc\n\t"
        "s_waitcnt vmcnt(0)\n\t"
        "v_mov_b32 v44, v40\n\t" "v_mov_b32 v45, v41\n\t" "v_mov_b32 v46, v42\n\t"
        "global_load_dwordx2 v[40:41], v[12:13], off\n\t"
        "global_load_dword v42, v[14:15], off\n\t"
        "v_add_co_u32 v12, vcc, 0x200, v12\n\t"
        "v_addc_co_u32 v13, vcc, 0, v13, vcc\n\t"
        "v_add_co_u32 v14, vcc, 4, v14\n\t"
        "v_addc_co_u32 v15, vcc, 0, v15, vcc\n\t"
        "s_movk_i32 s48, 200\n\t"
        "Lrec%=:\n\t"
        ACC_ZERO
        DOT64
        // sums: sR -> v50, sG -> v52
        "v_add_f32 v50, v32, v33\n\t"
        "v_add_f32 v51, v34, v35\n\t"
        "v_add_f32 v52, v36, v37\n\t"
        "v_add_f32 v53, v38, v39\n\t"
        "v_add_f32 v50, v50, v51\n\t"
        "v_add_f32 v52, v52, v53\n\t"
        // gates: r = sigmoid(pv.x + sR); hc = tanh(pv.y + r*(sG+bg))
        "v_add_f32 v50, v44, v50\n\t"              // zr
        "v_add_f32 v52, v9, v52\n\t"               // sG + bg
        "v_mul_f32 v50, 0xbfb8aa3b, v50\n\t"       // -zr*log2e
        "v_exp_f32 v50, v50\n\t"
        "s_nop 1\n\t"
        "v_add_f32 v50, 1.0, v50\n\t"
        "v_rcp_f32 v50, v50\n\t"                   // r
        "s_nop 1\n\t"
        "v_mul_f32 v52, v50, v52\n\t"
        "v_add_f32 v52, v45, v52\n\t"              // zh
        "v_mul_f32 v52, 0x4038aa3b, v52\n\t"       // zh*2*log2e
        "v_exp_f32 v52, v52\n\t"
        "s_nop 1\n\t"
        "v_add_f32 v52, 1.0, v52\n\t"
        "v_rcp_f32 v52, v52\n\t"
        "s_nop 1\n\t"
        "v_fma_f32 v52, -2.0, v52, 1.0\n\t"        // hc
        "v_sub_f32 v53, v52, v8\n\t"
        "v_fmac_f32 v8, v46, v53\n\t"              // h += av*(hc-h)
        // store h: store(t-1) must retire before reusing v43
        "s_waitcnt vmcnt(2)\n\t"
        "v_mov_b32 v43, v8\n\t"
        "global_store_dword v[16:17], v43, off\n\t"
        "v_add_co_u32 v16, vcc, 0x100, v16\n\t"
        "v_addc_co_u32 v17, vcc, 0, v17, vcc\n\t"
        // rotate prefetch (loads t+1 landed); issue loads t+2 (clamped)
        "s_waitcnt vmcnt(1)\n\t"
        "v_mov_b32 v44, v40\n\t" "v_mov_b32 v45, v41\n\t" "v_mov_b32 v46, v42\n\t"
        "global_load_dwordx2 v[40:41], v[12:13], off\n\t"
        "global_load_dword v42, v[14:15], off\n\t"
        "s_sub_u32 s48, s48, 1\n\t"
        "s_cmp_ge_u32 s48, 3\n\t"
        "s_cselect_b32 s49, 0x200, 0\n\t"
        "s_cselect_b32 s50, 4, 0\n\t"
        "v_add_co_u32 v12, vcc, s49, v12\n\t"
        "v_addc_co_u32 v13, vcc, 0, v13, vcc\n\t"
        "v_add_co_u32 v14, vcc, s50, v14\n\t"
        "v_addc_co_u32 v15, vcc, 0, v15, vcc\n\t"
        "s_cmp_lg_u32 s48, 0\n\t"
        "s_cbranch_scc1 Lrec%=\n\t"
        "s_waitcnt vmcnt(0)\n\t"
        :
        : [walo]"v"(PTRLO(wa)), [wahi]"v"(PTRHI(wa)),
          [wblo]"v"(PTRLO(wb)), [wbhi]"v"(PTRHI(wb)),
          [prelo]"v"(PTRLO(pp)), [prehi]"v"(PTRHI(pp)),
          [attlo]"v"(PTRLO(ap)), [atthi]"v"(PTRHI(ap)),
          [outlo]"v"(PTRLO(op)), [outhi]"v"(PTRHI(op)),
          [h0v]"v"(h0v), [bgv]"v"(bgv)
        : ACLOBBERS);
}

// ---------------- Kernel 1: projections (asm core) ----------------
// 4096 blocks x 256 = 16384 waves; 409600 rows = 16384 * 25.
__global__ __launch_bounds__(256, 2) void proj_kernel(
    const float* __restrict__ x,  const float* __restrict__ w_ir,
    const float* __restrict__ w_ih, const float* __restrict__ b_ir,
    const float* __restrict__ b_hr, const float* __restrict__ b_ih,
    f32x2* __restrict__ pre)
{
    const int u   = threadIdx.x & 63;
    const int wid = (int)((blockIdx.x * blockDim.x + threadIdx.x) >> 6);

    const float* wa = w_ir + u;
    const float* wb = w_ih + u;
    const float* xb = x + (size_t)wid * UDIM + u;
    f32x2*       po = pre + (size_t)wid * UDIM + u;
    const float brv = b_ir[u] + b_hr[u];
    const float bhv = b_ih[u];

    asm volatile(
        "v_mov_b32 v10, %[walo]\n\t" "v_mov_b32 v11, %[wahi]\n\t"
        WLOAD_A
        "v_mov_b32 v10, %[wblo]\n\t" "v_mov_b32 v11, %[wbhi]\n\t"
        WLOAD_B
        "v_mov_b32 v12, %[xlo]\n\t"  "v_mov_b32 v13, %[xhi]\n\t"
        "v_mov_b32 v16, %[outlo]\n\t" "v_mov_b32 v17, %[outhi]\n\t"
        "s_mov_b32 s51, 0x400000\n\t"      // x stride: 16384 rows * 256B
        "s_mov_b32 s52, 0x800000\n\t"      // pre stride: 16384 rows * 512B
        // prologue: x(0) -> v44 (waits weights too); issue x(1)
        "global_load_dword v40, v[12:13], off\n\t"
        "v_add_co_u32 v12, vcc, s51, v12\n\t"
        "v_addc_co_u32 v13, vcc, 0, v13, vcc\n\t"
        "s_waitcnt vmcnt(0)\n\t"
        "v_mov_b32 v44, v40\n\t"
        "global_load_dword v40, v[12:13], off\n\t"
        "v_add_co_u32 v12, vcc, s51, v12\n\t"
        "v_addc_co_u32 v13, vcc, 0, v13, vcc\n\t"
        "s_movk_i32 s48, 25\n\t"
        "Lproj%=:\n\t"
        "v_mov_b32 v8, v44\n\t"            // hoisted: 9 instrs before readlane
        ACC_ZERO
        DOT64
        // sums into v50/v51 (v42 temp); v52/53 still owned by store(i-1)
        "v_add_f32 v50, v32, v33\n\t"
        "v_add_f32 v42, v34, v35\n\t"
        "v_add_f32 v50, v50, v42\n\t"      // sR
        "v_add_f32 v51, v36, v37\n\t"
        "v_add_f32 v42, v38, v39\n\t"
        "v_add_f32 v51, v51, v42\n\t"      // sG
        "s_waitcnt vmcnt(1)\n\t"           // retire store(i-1): v52/53 free
        "v_add_f32 v52, %[brv], v50\n\t"
        "v_add_f32 v53, %[bhv], v51\n\t"
        "global_store_dwordx2 v[16:17], v[52:53], off\n\t"
        "v_add_co_u32 v16, vcc, s52, v16\n\t"
        "v_addc_co_u32 v17, vcc, 0, v17, vcc\n\t"
        "s_waitcnt vmcnt(1)\n\t"           // x(i+1) landed (store(i) pending)
        "v_mov_b32 v44, v40\n\t"
        "global_load_dword v40, v[12:13], off\n\t"
        "s_sub_u32 s48, s48, 1\n\t"
        "s_cmp_ge_u32 s48, 3\n\t"
        "s_cselect_b32 s49, s51, 0\n\t"
        "v_add_co_u32 v12, vcc, s49, v12\n\t"
        "v_addc_co_u32 v13, vcc, 0, v13, vcc\n\t"
        "s_cmp_lg_u32 s48, 0\n\t"
        "s_cbranch_scc1 Lproj%=\n\t"
        "s_waitcnt vmcnt(0)\n\t"
        :
        : [walo]"v"(PTRLO(wa)), [wahi]"v"(PTRHI(wa)),
          [wblo]"v"(PTRLO(wb)), [wbhi]"v"(PTRHI(wb)),
          [xlo]"v"(PTRLO(xb)),  [xhi]"v"(PTRHI(xb)),
          [outlo]"v"(PTRLO(po)), [outhi]"v"(PTRHI(po)),
          [brv]"v"(brv), [bhv]"v"(bhv)
        : ACLOBBERS);
}

// ---------------- Fallback: fused kernel (small ws) ----------------
__device__ __forceinline__ float lane_bcast(float v, int lane) {
    return __builtin_bit_cast(float, __builtin_amdgcn_readlane(__builtin_bit_cast(int, v), lane));
}
__device__ __forceinline__ float fast_sigmoid(float z) {
    return __builtin_amdgcn_rcpf(1.0f + __expf(-z));
}
__device__ __forceinline__ float fast_tanh(float z) {
    return 1.0f - 2.0f * __builtin_amdgcn_rcpf(__expf(2.0f * z) + 1.0f);
}

__global__ __launch_bounds__(256) void agru_fused_kernel(
    const float* __restrict__ x, const float* __restrict__ att,
    const float* __restrict__ h0,
    const float* __restrict__ w_ir, const float* __restrict__ w_hr,
    const float* __restrict__ b_ir, const float* __restrict__ b_hr,
    const float* __restrict__ w_ih, const float* __restrict__ w_hh,
    const float* __restrict__ b_ih, const float* __restrict__ b_hh,
    float* __restrict__ out)
{
    __shared__ float lds[4 * UDIM * UDIM];
    const int tid = threadIdx.x;
    #pragma unroll
    for (int i = 0; i < 16; ++i) {
        int e = tid + 256 * i;
        lds[e] = w_ir[e]; lds[4096 + e] = w_ih[e];
        lds[8192 + e] = w_hr[e]; lds[12288 + e] = w_hh[e];
    }
    __syncthreads();

    const int wave = tid >> 6;
    const int u = tid & 63;
    const int r0 = blockIdx.x * 8 + wave * 2;
    const int r1 = r0 + 1;

    float h_0 = h0[r0 * UDIM + u];
    float h_1 = h0[r1 * UDIM + u];
    const float bR = b_ir[u] + b_hr[u];
    const float bH = b_ih[u];
    const float bG = b_hh[u];

    const float* xp0 = x + (long)r0 * T_STEPS * UDIM + u;
    const float* xp1 = x + (long)r1 * T_STEPS * UDIM + u;
    const float* ap0 = att + (long)r0 * T_STEPS;
    const float* ap1 = att + (long)r1 * T_STEPS;
    float* op0 = out + (long)r0 * T_STEPS * UDIM + u;
    float* op1 = out + (long)r1 * T_STEPS * UDIM + u;

    float xv0 = xp0[0], xv1 = xp1[0], a0 = ap0[0], a1 = ap1[0];

    for (int t = 0; t < T_STEPS; ++t) {
        const int tn = (t + 1 < T_STEPS) ? (t + 1) : t;
        float nxv0 = xp0[(long)tn * UDIM], nxv1 = xp1[(long)tn * UDIM];
        float na0 = ap0[tn], na1 = ap1[tn];

        float accR0 = bR, accR1 = bR, accH0 = bH, accH1 = bH, accG0 = bG, accG1 = bG;
        #pragma unroll
        for (int j = 0; j < 64; ++j) {
            const float wir = lds[j * 64 + u];
            const float wih = lds[4096 + j * 64 + u];
            const float whr = lds[8192 + j * 64 + u];
            const float whh = lds[12288 + j * 64 + u];
            const float xj0 = lane_bcast(xv0, j);
            const float xj1 = lane_bcast(xv1, j);
            const float hj0 = lane_bcast(h_0, j);
            const float hj1 = lane_bcast(h_1, j);
            accR0 = fmaf(xj0, wir, accR0); accR0 = fmaf(hj0, whr, accR0);
            accH0 = fmaf(xj0, wih, accH0); accG0 = fmaf(hj0, whh, accG0);
            accR1 = fmaf(xj1, wir, accR1); accR1 = fmaf(hj1, whr, accR1);
            accH1 = fmaf(xj1, wih, accH1); accG1 = fmaf(hj1, whh, accG1);
        }
        const float r0g = fast_sigmoid(accR0);
        const float r1g = fast_sigmoid(accR1);
        const float hc0 = fast_tanh(fmaf(r0g, accG0, accH0));
        const float hc1 = fast_tanh(fmaf(r1g, accG1, accH1));
        h_0 = fmaf(a0, hc0 - h_0, h_0);
        h_1 = fmaf(a1, hc1 - h_1, h_1);
        op0[(long)t * UDIM] = h_0;
        op1[(long)t * UDIM] = h_1;
        xv0 = nxv0; xv1 = nxv1; a0 = na0; a1 = na1;
    }
}

extern "C" void kernel_launch(void* const* d_in, const int* in_sizes, int n_in,
                              void* d_out, int out_size, void* d_ws, size_t ws_size,
                              hipStream_t stream) {
    (void)in_sizes; (void)n_in; (void)out_size;

    const float* x    = (const float*)d_in[0];
    const float* att  = (const float*)d_in[1];
    const float* h0   = (const float*)d_in[2];
    const float* w_ir = (const float*)d_in[3];
    const float* w_hr = (const float*)d_in[4];
    const float* b_ir = (const float*)d_in[5];
    const float* b_hr = (const float*)d_in[6];
    const float* w_ih = (const float*)d_in[7];
    const float* w_hh = (const float*)d_in[8];
    const float* b_ih = (const float*)d_in[9];
    const float* b_hh = (const float*)d_in[10];
    float* out = (float*)d_out;

    const size_t pre_bytes = (size_t)NROWS * UDIM * sizeof(f32x2); // 210 MB

    if (ws_size >= pre_bytes) {
        f32x2* pre = (f32x2*)d_ws;
        proj_kernel<<<dim3(4096), dim3(256), 0, stream>>>(
            x, w_ir, w_ih, b_ir, b_hr, b_ih, pre);
        rec_kernel<<<dim3(512), dim3(256), 0, stream>>>(
            pre, att, h0, w_hr, w_hh, b_hh, out);
    } else {
        agru_fused_kernel<<<dim3(256), dim3(256), 0, stream>>>(
            x, att, h0, w_ir, w_hr, b_ir, b_hr, w_ih, w_hh, b_ih, b_hh, out);
    }
}

// Round 11
// 269.476 us; speedup vs baseline: 1.3170x; 1.3170x over previous
//
#include <hip/hip_runtime.h>

// AGRU: B=2048, T=200, D=U=64, fp32. v10 = best-of-breed frankenstein.
//  - rec: v9's verified explicit-register asm pipeline, DOT reworked to
//    v_pk_fma_f32: per 2 j's -> 2 readlanes into an even SGPR pair +
//    1 pk_fma per matrix (A rows in v64-127, B rows in v128-191; adjacent
//    even-aligned pairs). 128 VALU/step vs v9's 192. (pk+SGPR-pair proven
//    on-silicon in r4: compiled, passed absmax 0.0039.)
//  - proj: the round-3 compiler version verbatim (measured ~105us): float2
//    w2[64] array, 4-row groups with prefetch, launch_bounds(256,3).
// All f32 (r7: f16 weights diverge, absmax 1.96). Fast sigmoid/tanh via
// v_exp/v_rcp (proven absmax ~0.004).

typedef float f32x2 __attribute__((ext_vector_type(2)));

constexpr int BATCH = 2048;
constexpr int T_STEPS = 200;
constexpr int UDIM = 64;
constexpr int NROWS = BATCH * T_STEPS;   // 409600

#define STR_(x) #x
#define STR(x) STR_(x)

#define PTRLO(p) ((unsigned)(unsigned long long)(const void*)(p))
#define PTRHI(p) ((unsigned)(((unsigned long long)(const void*)(p)) >> 32))

__device__ __forceinline__ float lane_bcast(float v, int lane) {
    return __builtin_bit_cast(float, __builtin_amdgcn_readlane(__builtin_bit_cast(int, v), lane));
}
__device__ __forceinline__ float fast_sigmoid(float z) {
    return __builtin_amdgcn_rcpf(1.0f + __expf(-z));
}
__device__ __forceinline__ float fast_tanh(float z) {
    return 1.0f - 2.0f * __builtin_amdgcn_rcpf(__expf(2.0f * z) + 1.0f);
}

// ---- weight loads: 128 coalesced dword loads into v64..v191 ----
#define WLD(R,O) "global_load_dword v" STR(R) ", v[10:11], off offset:" STR(O) "\n\t"
#define WBUMP \
  "v_add_co_u32 v10, vcc, 0x1000, v10\n\t" \
  "v_addc_co_u32 v11, vcc, 0, v11, vcc\n\t"

#define WIN16(R0,R1,R2,R3,R4,R5,R6,R7,R8,R9,R10,R11,R12,R13,R14,R15) \
  WLD(R0,0) WLD(R1,256) WLD(R2,512) WLD(R3,768) \
  WLD(R4,1024) WLD(R5,1280) WLD(R6,1536) WLD(R7,1792) \
  WLD(R8,2048) WLD(R9,2304) WLD(R10,2560) WLD(R11,2816) \
  WLD(R12,3072) WLD(R13,3328) WLD(R14,3584) WLD(R15,3840)

#define WLOAD_A \
  WIN16(64,65,66,67,68,69,70,71,72,73,74,75,76,77,78,79) WBUMP \
  WIN16(80,81,82,83,84,85,86,87,88,89,90,91,92,93,94,95) WBUMP \
  WIN16(96,97,98,99,100,101,102,103,104,105,106,107,108,109,110,111) WBUMP \
  WIN16(112,113,114,115,116,117,118,119,120,121,122,123,124,125,126,127)

#define WLOAD_B \
  WIN16(128,129,130,131,132,133,134,135,136,137,138,139,140,141,142,143) WBUMP \
  WIN16(144,145,146,147,148,149,150,151,152,153,154,155,156,157,158,159) WBUMP \
  WIN16(160,161,162,163,164,165,166,167,168,169,170,171,172,173,174,175) WBUMP \
  WIN16(176,177,178,179,180,181,182,183,184,185,186,187,188,189,190,191)

// ---- PKQUAD: 4 j's = 4 readlanes (s40-s43) + 4 pk_fma (2 per matrix) ----
// v32 += s40*A[j0], v33 += s41*A[j1]  (chain {v32:v33} = A)
// v36 += s40*B[j0], v37 += s41*B[j1]  (chain {v36:v37} = B), etc.
#define PKQUAD(J0,J1,J2,J3, A0,A0b,A2,A2b, B0,B0b,B2,B2b) \
  "v_readlane_b32 s40, v8, " STR(J0) "\n\t" \
  "v_readlane_b32 s41, v8, " STR(J1) "\n\t" \
  "v_readlane_b32 s42, v8, " STR(J2) "\n\t" \
  "v_readlane_b32 s43, v8, " STR(J3) "\n\t" \
  "v_pk_fma_f32 v[32:33], s[40:41], v[" STR(A0) ":" STR(A0b) "], v[32:33]\n\t" \
  "v_pk_fma_f32 v[36:37], s[40:41], v[" STR(B0) ":" STR(B0b) "], v[36:37]\n\t" \
  "v_pk_fma_f32 v[34:35], s[42:43], v[" STR(A2) ":" STR(A2b) "], v[34:35]\n\t" \
  "v_pk_fma_f32 v[38:39], s[42:43], v[" STR(B2) ":" STR(B2b) "], v[38:39]\n\t"

#define DOT64PK \
  PKQUAD(0,1,2,3,     64,65,66,67,    128,129,130,131) \
  PKQUAD(4,5,6,7,     68,69,70,71,    132,133,134,135) \
  PKQUAD(8,9,10,11,   72,73,74,75,    136,137,138,139) \
  PKQUAD(12,13,14,15, 76,77,78,79,    140,141,142,143) \
  PKQUAD(16,17,18,19, 80,81,82,83,    144,145,146,147) \
  PKQUAD(20,21,22,23, 84,85,86,87,    148,149,150,151) \
  PKQUAD(24,25,26,27, 88,89,90,91,    152,153,154,155) \
  PKQUAD(28,29,30,31, 92,93,94,95,    156,157,158,159) \
  PKQUAD(32,33,34,35, 96,97,98,99,    160,161,162,163) \
  PKQUAD(36,37,38,39, 100,101,102,103,164,165,166,167) \
  PKQUAD(40,41,42,43, 104,105,106,107,168,169,170,171) \
  PKQUAD(44,45,46,47, 108,109,110,111,172,173,174,175) \
  PKQUAD(48,49,50,51, 112,113,114,115,176,177,178,179) \
  PKQUAD(52,53,54,55, 116,117,118,119,180,181,182,183) \
  PKQUAD(56,57,58,59, 120,121,122,123,184,185,186,187) \
  PKQUAD(60,61,62,63, 124,125,126,127,188,189,190,191)

#define ACC_ZERO \
  "v_mov_b32 v32, 0\n\t" "v_mov_b32 v33, 0\n\t" \
  "v_mov_b32 v34, 0\n\t" "v_mov_b32 v35, 0\n\t" \
  "v_mov_b32 v36, 0\n\t" "v_mov_b32 v37, 0\n\t" \
  "v_mov_b32 v38, 0\n\t" "v_mov_b32 v39, 0\n\t"

#define ACLOBBERS \
  "v8","v9","v10","v11","v12","v13","v14","v15","v16","v17", \
  "v32","v33","v34","v35","v36","v37","v38","v39","v40","v41","v42","v43", \
  "v44","v45","v46","v50","v51","v52","v53", \
  "v64","v65","v66","v67","v68","v69","v70","v71", \
  "v72","v73","v74","v75","v76","v77","v78","v79", \
  "v80","v81","v82","v83","v84","v85","v86","v87", \
  "v88","v89","v90","v91","v92","v93","v94","v95", \
  "v96","v97","v98","v99","v100","v101","v102","v103", \
  "v104","v105","v106","v107","v108","v109","v110","v111", \
  "v112","v113","v114","v115","v116","v117","v118","v119", \
  "v120","v121","v122","v123","v124","v125","v126","v127", \
  "v128","v129","v130","v131","v132","v133","v134","v135", \
  "v136","v137","v138","v139","v140","v141","v142","v143", \
  "v144","v145","v146","v147","v148","v149","v150","v151", \
  "v152","v153","v154","v155","v156","v157","v158","v159", \
  "v160","v161","v162","v163","v164","v165","v166","v167", \
  "v168","v169","v170","v171","v172","v173","v174","v175", \
  "v176","v177","v178","v179","v180","v181","v182","v183", \
  "v184","v185","v186","v187","v188","v189","v190","v191", \
  "s40","s41","s42","s43","s48","s49","s50","vcc","scc","memory"

// ---------------- Kernel 2: recurrence (pk asm core) ----------------
// 512 blocks x 256 = 2048 waves (2/SIMD), 1 batch row per wave.
__global__ __launch_bounds__(256, 2) void rec_kernel(
    const f32x2* __restrict__ pre, const float* __restrict__ att,
    const float* __restrict__ h0,  const float* __restrict__ w_hr,
    const float* __restrict__ w_hh,const float* __restrict__ b_hh,
    float* __restrict__ out)
{
    const int u   = threadIdx.x & 63;
    const int row = (int)((blockIdx.x * blockDim.x + threadIdx.x) >> 6);

    const float* wa = w_hr + u;
    const float* wb = w_hh + u;
    const f32x2* pp = pre + (size_t)row * T_STEPS * UDIM + u;
    const float* ap = att + (size_t)row * T_STEPS;
    float*       op = out + (size_t)row * T_STEPS * UDIM + u;
    const float h0v = h0[(size_t)row * UDIM + u];
    const float bgv = b_hh[u];

    asm volatile(
        "v_mov_b32 v10, %[walo]\n\t" "v_mov_b32 v11, %[wahi]\n\t"
        WLOAD_A
        "v_mov_b32 v10, %[wblo]\n\t" "v_mov_b32 v11, %[wbhi]\n\t"
        WLOAD_B
        "v_mov_b32 v12, %[prelo]\n\t" "v_mov_b32 v13, %[prehi]\n\t"
        "v_mov_b32 v14, %[attlo]\n\t" "v_mov_b32 v15, %[atthi]\n\t"
        "v_mov_b32 v16, %[outlo]\n\t" "v_mov_b32 v17, %[outhi]\n\t"
        "v_mov_b32 v8, %[h0v]\n\t"
        "v_mov_b32 v9, %[bgv]\n\t"
        // prologue: load pv(0),av(0); wait all (incl. weights); issue pv(1),av(1)
        "global_load_dwordx2 v[40:41], v[12:13], off\n\t"
        "global_load_dword v42, v[14:15], off\n\t"
        "v_add_co_u32 v12, vcc, 0x200, v12\n\t"
        "v_addc_co_u32 v13, vcc, 0, v13, vcc\n\t"
        "v_add_co_u32 v14, vcc, 4, v14\n\t"
        "v_addc_co_u32 v15, vcc, 0, v15, vcc\n\t"
        "s_waitcnt vmcnt(0)\n\t"
        "v_mov_b32 v44, v40\n\t" "v_mov_b32 v45, v41\n\t" "v_mov_b32 v46, v42\n\t"
        "global_load_dwordx2 v[40:41], v[12:13], off\n\t"
        "global_load_dword v42, v[14:15], off\n\t"
        "v_add_co_u32 v12, vcc, 0x200, v12\n\t"
        "v_addc_co_u32 v13, vcc, 0, v13, vcc\n\t"
        "v_add_co_u32 v14, vcc, 4, v14\n\t"
        "v_addc_co_u32 v15, vcc, 0, v15, vcc\n\t"
        "s_movk_i32 s48, 200\n\t"
        "Lrec%=:\n\t"
        ACC_ZERO
        DOT64PK
        // sums: sR = v32+..+v35 -> v50 ; sG = v36+..+v39 -> v52
        "v_add_f32 v50, v32, v33\n\t"
        "v_add_f32 v51, v34, v35\n\t"
        "v_add_f32 v52, v36, v37\n\t"
        "v_add_f32 v53, v38, v39\n\t"
        "v_add_f32 v50, v50, v51\n\t"
        "v_add_f32 v52, v52, v53\n\t"
        // gates: r = sigmoid(pv.x + sR); hc = tanh(pv.y + r*(sG+bg))
        "v_add_f32 v50, v44, v50\n\t"              // zr
        "v_add_f32 v52, v9, v52\n\t"               // sG + bg
        "v_mul_f32 v50, 0xbfb8aa3b, v50\n\t"       // -zr*log2e
        "v_exp_f32 v50, v50\n\t"
        "s_nop 1\n\t"
        "v_add_f32 v50, 1.0, v50\n\t"
        "v_rcp_f32 v50, v50\n\t"                   // r
        "s_nop 1\n\t"
        "v_mul_f32 v52, v50, v52\n\t"
        "v_add_f32 v52, v45, v52\n\t"              // zh
        "v_mul_f32 v52, 0x4038aa3b, v52\n\t"       // zh*2*log2e
        "v_exp_f32 v52, v52\n\t"
        "s_nop 1\n\t"
        "v_add_f32 v52, 1.0, v52\n\t"
        "v_rcp_f32 v52, v52\n\t"
        "s_nop 1\n\t"
        "v_fma_f32 v52, -2.0, v52, 1.0\n\t"        // hc
        "v_sub_f32 v53, v52, v8\n\t"
        "v_fmac_f32 v8, v46, v53\n\t"              // h += av*(hc-h)
        // store h: store(t-1) must retire before reusing v43
        "s_waitcnt vmcnt(2)\n\t"
        "v_mov_b32 v43, v8\n\t"
        "global_store_dword v[16:17], v43, off\n\t"
        "v_add_co_u32 v16, vcc, 0x100, v16\n\t"
        "v_addc_co_u32 v17, vcc, 0, v17, vcc\n\t"
        // rotate prefetch (loads t+1 landed); issue loads t+2 (clamped)
        "s_waitcnt vmcnt(1)\n\t"
        "v_mov_b32 v44, v40\n\t" "v_mov_b32 v45, v41\n\t" "v_mov_b32 v46, v42\n\t"
        "global_load_dwordx2 v[40:41], v[12:13], off\n\t"
        "global_load_dword v42, v[14:15], off\n\t"
        "s_sub_u32 s48, s48, 1\n\t"
        "s_cmp_ge_u32 s48, 3\n\t"
        "s_cselect_b32 s49, 0x200, 0\n\t"
        "s_cselect_b32 s50, 4, 0\n\t"
        "v_add_co_u32 v12, vcc, s49, v12\n\t"
        "v_addc_co_u32 v13, vcc, 0, v13, vcc\n\t"
        "v_add_co_u32 v14, vcc, s50, v14\n\t"
        "v_addc_co_u32 v15, vcc, 0, v15, vcc\n\t"
        "s_cmp_lg_u32 s48, 0\n\t"
        "s_cbranch_scc1 Lrec%=\n\t"
        "s_waitcnt vmcnt(0)\n\t"
        :
        : [walo]"v"(PTRLO(wa)), [wahi]"v"(PTRHI(wa)),
          [wblo]"v"(PTRLO(wb)), [wbhi]"v"(PTRHI(wb)),
          [prelo]"v"(PTRLO(pp)), [prehi]"v"(PTRHI(pp)),
          [attlo]"v"(PTRLO(ap)), [atthi]"v"(PTRHI(ap)),
          [outlo]"v"(PTRLO(op)), [outhi]"v"(PTRHI(op)),
          [h0v]"v"(h0v), [bgv]"v"(bgv)
        : ACLOBBERS);
}

// ---------------- Kernel 1: projections (round-3 verbatim) ----------------
// 1024 blocks x 256 = 4096 waves; 409600 rows = 4096 waves * 25 groups * 4.
__global__ __launch_bounds__(256, 3) void proj_kernel(
    const float* __restrict__ x,     // [B*T,64]
    const float* __restrict__ w_ir,  // [64,64]
    const float* __restrict__ w_ih,  // [64,64]
    const float* __restrict__ b_ir,
    const float* __restrict__ b_hr,
    const float* __restrict__ b_ih,
    f32x2* __restrict__ pre)         // [B*T,64] of {pre_r, pre_h}
{
    const int u = threadIdx.x & 63;

    f32x2 w2[UDIM];
    #pragma unroll
    for (int j = 0; j < UDIM; ++j) {
        w2[j].x = w_ir[j * UDIM + u];   // coalesced 256B row reads
        w2[j].y = w_ih[j * UDIM + u];
    }
    const float br = b_ir[u] + b_hr[u];
    const float bh = b_ih[u];

    const int nwaves = (int)((gridDim.x * blockDim.x) >> 6);       // 4096
    const int wid = (int)((blockIdx.x * blockDim.x + threadIdx.x) >> 6);

    const int ngroups = NROWS / 4;                                  // 102400
    const float* xp = x + u;

    long r = (long)wid * 4;
    float xa = xp[(r + 0) * UDIM];
    float xb = xp[(r + 1) * UDIM];
    float xc = xp[(r + 2) * UDIM];
    float xd = xp[(r + 3) * UDIM];

    for (int g = wid; g < ngroups; g += nwaves) {
        const int gn = (g + nwaves < ngroups) ? (g + nwaves) : g;
        const long rn = (long)gn * 4;
        float na = xp[(rn + 0) * UDIM];
        float nb = xp[(rn + 1) * UDIM];
        float nc = xp[(rn + 2) * UDIM];
        float nd = xp[(rn + 3) * UDIM];

        f32x2* po = pre + (long)g * 4 * UDIM + u;

        #pragma unroll
        for (int k = 0; k < 4; ++k) {
            const float xv = (k == 0) ? xa : (k == 1) ? xb : (k == 2) ? xc : xd;
            f32x2 accA; accA.x = br;  accA.y = bh;
            f32x2 accB; accB.x = 0.f; accB.y = 0.f;
            #pragma unroll
            for (int j = 0; j < UDIM; j += 2) {
                const float s0 = lane_bcast(xv, j);
                const float s1 = lane_bcast(xv, j + 1);
                accA.x = fmaf(s0, w2[j].x,     accA.x);
                accA.y = fmaf(s0, w2[j].y,     accA.y);
                accB.x = fmaf(s1, w2[j + 1].x, accB.x);
                accB.y = fmaf(s1, w2[j + 1].y, accB.y);
            }
            f32x2 o; o.x = accA.x + accB.x; o.y = accA.y + accB.y;
            po[(long)k * UDIM] = o;     // global_store_dwordx2
        }

        xa = na; xb = nb; xc = nc; xd = nd;
    }
}

// ---------------- Fallback: fused kernel (small ws) ----------------
__global__ __launch_bounds__(256) void agru_fused_kernel(
    const float* __restrict__ x, const float* __restrict__ att,
    const float* __restrict__ h0,
    const float* __restrict__ w_ir, const float* __restrict__ w_hr,
    const float* __restrict__ b_ir, const float* __restrict__ b_hr,
    const float* __restrict__ w_ih, const float* __restrict__ w_hh,
    const float* __restrict__ b_ih, const float* __restrict__ b_hh,
    float* __restrict__ out)
{
    __shared__ float lds[4 * UDIM * UDIM];
    const int tid = threadIdx.x;
    #pragma unroll
    for (int i = 0; i < 16; ++i) {
        int e = tid + 256 * i;
        lds[e] = w_ir[e]; lds[4096 + e] = w_ih[e];
        lds[8192 + e] = w_hr[e]; lds[12288 + e] = w_hh[e];
    }
    __syncthreads();

    const int wave = tid >> 6;
    const int u = tid & 63;
    const int r0 = blockIdx.x * 8 + wave * 2;
    const int r1 = r0 + 1;

    float h_0 = h0[r0 * UDIM + u];
    float h_1 = h0[r1 * UDIM + u];
    const float bR = b_ir[u] + b_hr[u];
    const float bH = b_ih[u];
    const float bG = b_hh[u];

    const float* xp0 = x + (long)r0 * T_STEPS * UDIM + u;
    const float* xp1 = x + (long)r1 * T_STEPS * UDIM + u;
    const float* ap0 = att + (long)r0 * T_STEPS;
    const float* ap1 = att + (long)r1 * T_STEPS;
    float* op0 = out + (long)r0 * T_STEPS * UDIM + u;
    float* op1 = out + (long)r1 * T_STEPS * UDIM + u;

    float xv0 = xp0[0], xv1 = xp1[0], a0 = ap0[0], a1 = ap1[0];

    for (int t = 0; t < T_STEPS; ++t) {
        const int tn = (t + 1 < T_STEPS) ? (t + 1) : t;
        float nxv0 = xp0[(long)tn * UDIM], nxv1 = xp1[(long)tn * UDIM];
        float na0 = ap0[tn], na1 = ap1[tn];

        float accR0 = bR, accR1 = bR, accH0 = bH, accH1 = bH, accG0 = bG, accG1 = bG;
        #pragma unroll
        for (int j = 0; j < 64; ++j) {
            const float wir = lds[j * 64 + u];
            const float wih = lds[4096 + j * 64 + u];
            const float whr = lds[8192 + j * 64 + u];
            const float whh = lds[12288 + j * 64 + u];
            const float xj0 = lane_bcast(xv0, j);
            const float xj1 = lane_bcast(xv1, j);
            const float hj0 = lane_bcast(h_0, j);
            const float hj1 = lane_bcast(h_1, j);
            accR0 = fmaf(xj0, wir, accR0); accR0 = fmaf(hj0, whr, accR0);
            accH0 = fmaf(xj0, wih, accH0); accG0 = fmaf(hj0, whh, accG0);
            accR1 = fmaf(xj1, wir, accR1); accR1 = fmaf(hj1, whr, accR1);
            accH1 = fmaf(xj1, wih, accH1); accG1 = fmaf(hj1, whh, accG1);
        }
        const float r0g = fast_sigmoid(accR0);
        const float r1g = fast_sigmoid(accR1);
        const float hc0 = fast_tanh(fmaf(r0g, accG0, accH0));
        const float hc1 = fast_tanh(fmaf(r1g, accG1, accH1));
        h_0 = fmaf(a0, hc0 - h_0, h_0);
        h_1 = fmaf(a1, hc1 - h_1, h_1);
        op0[(long)t * UDIM] = h_0;
        op1[(long)t * UDIM] = h_1;
        xv0 = nxv0; xv1 = nxv1; a0 = na0; a1 = na1;
    }
}

extern "C" void kernel_launch(void* const* d_in, const int* in_sizes, int n_in,
                              void* d_out, int out_size, void* d_ws, size_t ws_size,
                              hipStream_t stream) {
    (void)in_sizes; (void)n_in; (void)out_size;

    const float* x    = (const float*)d_in[0];
    const float* att  = (const float*)d_in[1];
    const float* h0   = (const float*)d_in[2];
    const float* w_ir = (const float*)d_in[3];
    const float* w_hr = (const float*)d_in[4];
    const float* b_ir = (const float*)d_in[5];
    const float* b_hr = (const float*)d_in[6];
    const float* w_ih = (const float*)d_in[7];
    const float* w_hh = (const float*)d_in[8];
    const float* b_ih = (const float*)d_in[9];
    const float* b_hh = (const float*)d_in[10];
    float* out = (float*)d_out;

    const size_t pre_bytes = (size_t)NROWS * UDIM * sizeof(f32x2); // 210 MB

    if (ws_size >= pre_bytes) {
        f32x2* pre = (f32x2*)d_ws;
        proj_kernel<<<dim3(1024), dim3(256), 0, stream>>>(
            x, w_ir, w_ih, b_ir, b_hr, b_ih, pre);
        rec_kernel<<<dim3(512), dim3(256), 0, stream>>>(
            pre, att, h0, w_hr, w_hh, b_hh, out);
    } else {
        agru_fused_kernel<<<dim3(256), dim3(256), 0, stream>>>(
            x, att, h0, w_ir, w_hr, b_ir, b_hr, w_ih, w_hh, b_ih, b_hh, out);
    }
}